// Round 4
// baseline (721.456 us; speedup 1.0000x reference)
//
#include <hip/hip_runtime.h>

#define NLVL 16

typedef float f32x2 __attribute__((ext_vector_type(2)));
typedef float f32x4 __attribute__((ext_vector_type(4)));

// One block = one level x 1024 points (4 points per thread for gather ILP).
// blockIdx.x % 16 -> level via pairing (l, 15-l); XCD = blockIdx.x % 8 sees
// only levels {x, 15-x} -> fine table stays L2-resident per XCD.
__global__ __launch_bounds__(256, 4) void hashgrid_encode_ilp4(
    const float* __restrict__ xyz,
    const float* __restrict__ emb,
    const int*   __restrict__ offsets,
    const int*   __restrict__ resolutions,
    const float* __restrict__ min_xyz,
    const float* __restrict__ max_xyz,
    float* __restrict__ out,
    int B)
{
    const int g = blockIdx.x & 15;
    const int chunk = blockIdx.x >> 4;
    const int l = (g < 8) ? g : (23 - g);   // pairs (0,15),(1,14),...,(7,8)
    const int p0 = chunk * 1024 + (int)threadIdx.x * 4;
    if (p0 >= B) return;

    // wave-uniform level params
    const float res = (float)resolutions[l];
    const unsigned off  = (unsigned)offsets[l];
    const unsigned size = (unsigned)offsets[l + 1] - off;
    const unsigned mask = size - 1u;
    const bool pow2 = (size & mask) == 0u;
    const float mn0 = min_xyz[0], mn1 = min_xyz[1], mn2 = min_xyz[2];
    const float mx0 = max_xyz[0], mx1 = max_xyz[1], mx2 = max_xyz[2];
    const float2* __restrict__ lvl = reinterpret_cast<const float2*>(emb) + off;

    // ---- load 4 points' xyz (48B = 3 x float4, aligned since p0 % 4 == 0) ----
    float X[4], Y[4], Z[4];
    if (p0 + 4 <= B) {
        const f32x4* xp = reinterpret_cast<const f32x4*>(xyz + (size_t)p0 * 3);
        f32x4 v0 = xp[0], v1 = xp[1], v2 = xp[2];
        X[0] = v0.x; Y[0] = v0.y; Z[0] = v0.z;
        X[1] = v0.w; Y[1] = v1.x; Z[1] = v1.y;
        X[2] = v1.z; Y[2] = v1.w; Z[2] = v2.x;
        X[3] = v2.y; Y[3] = v2.z; Z[3] = v2.w;
    } else {
#pragma unroll
        for (int i = 0; i < 4; ++i) {
            int p = p0 + i; if (p > B - 1) p = B - 1;
            X[i] = xyz[p * 3 + 0]; Y[i] = xyz[p * 3 + 1]; Z[i] = xyz[p * 3 + 2];
        }
    }

    // ---- per-point setup: bit-exact fp32 chain (matches reference op order) ----
    float fx[4], fy[4], fz[4], qx[4], qy[4], qz[4];
    unsigned cx0[4], cy0[4], cz0[4];
    bool valid[4];
#pragma unroll
    for (int i = 0; i < 4; ++i) {
        float ux = (X[i] - mn0) / (mx0 - mn0);
        float uy = (Y[i] - mn1) / (mx1 - mn1);
        float uz = (Z[i] - mn2) / (mx2 - mn2);
        valid[i] = (ux >= 0.0f) & (ux <= 1.0f) &
                   (uy >= 0.0f) & (uy <= 1.0f) &
                   (uz >= 0.0f) & (uz <= 1.0f);
        float rm1 = res - 1.0f;
        float px = ux * res, py = uy * res, pz = uz * res;
        float p0x = fminf(fmaxf(floorf(px), 0.0f), rm1);
        float p0y = fminf(fmaxf(floorf(py), 0.0f), rm1);
        float p0z = fminf(fmaxf(floorf(pz), 0.0f), rm1);
        fx[i] = px - p0x; fy[i] = py - p0y; fz[i] = pz - p0z;
        qx[i] = 1.0f - fx[i]; qy[i] = 1.0f - fy[i]; qz[i] = 1.0f - fz[i];
        cx0[i] = (unsigned)p0x; cy0[i] = (unsigned)p0y; cz0[i] = (unsigned)p0z;
    }

    const unsigned P1 = 2654435761u;
    const unsigned P2 = 805459861u;

    // ---- issue all 32 gathers (independent -> deep vmem pipeline) ----
    float2 e[4][8];
#pragma unroll
    for (int i = 0; i < 4; ++i) {
#pragma unroll
        for (int c = 0; c < 8; ++c) {
            unsigned bx = (unsigned)(c & 1);
            unsigned by = (unsigned)((c >> 1) & 1);
            unsigned bz = (unsigned)((c >> 2) & 1);
            unsigned h = (cx0[i] + bx) ^ ((cy0[i] + by) * P1) ^ ((cz0[i] + bz) * P2);
            unsigned hm = pow2 ? (h & mask) : (h % size);
            e[i][c] = lvl[hm];
        }
    }

    // ---- accumulate (weights recomputed from frac regs; VALU is idle) ----
#pragma unroll
    for (int i = 0; i < 4; ++i) {
        float o0 = 0.0f, o1 = 0.0f;
#pragma unroll
        for (int c = 0; c < 8; ++c) {
            float w = ((c & 1) ? fx[i] : qx[i]) * ((c & 2) ? fy[i] : qy[i]);
            w = w * ((c & 4) ? fz[i] : qz[i]);
            o0 += w * e[i][c].x;
            o1 += w * e[i][c].y;
        }
        if (!valid[i]) { o0 = 0.0f; o1 = 0.0f; }
        int p = p0 + i;
        if (p < B) {
            f32x2 r; r.x = o0; r.y = o1;
            f32x2* op = reinterpret_cast<f32x2*>(out + (size_t)p * (NLVL * 2) + l * 2);
            __builtin_nontemporal_store(r, op);
        }
    }
}

extern "C" void kernel_launch(void* const* d_in, const int* in_sizes, int n_in,
                              void* d_out, int out_size, void* d_ws, size_t ws_size,
                              hipStream_t stream) {
    const float* xyz        = (const float*)d_in[0];
    const float* embeddings = (const float*)d_in[1];
    const int*   offsets    = (const int*)d_in[2];
    const int*   resolutions= (const int*)d_in[3];
    const float* min_xyz    = (const float*)d_in[4];
    const float* max_xyz    = (const float*)d_in[5];
    float* out = (float*)d_out;

    int B = in_sizes[0] / 3;
    int nchunks = (B + 1023) / 1024;
    int grid = nchunks * NLVL;
    hashgrid_encode_ilp4<<<grid, 256, 0, stream>>>(
        xyz, embeddings, offsets, resolutions, min_xyz, max_xyz, out, B);
}

// Round 5
// 712.962 us; speedup vs baseline: 1.0119x; 1.0119x over previous
//
#include <hip/hip_runtime.h>

#define NLVL 16
#define NDENSE 7            // levels 0..6: (res+1)^3 < 2^19 -> densify
#define PREPASS_CAP 600000  // max dense entries the pre-pass grid covers

typedef float f32x2 __attribute__((ext_vector_type(2)));
typedef float f32x4 __attribute__((ext_vector_type(4)));

__device__ __forceinline__ unsigned hash3(unsigned x, unsigned y, unsigned z) {
    return x ^ (y * 2654435761u) ^ (z * 805459861u);
}

__device__ __forceinline__ unsigned dense_total(const int* __restrict__ resolutions,
                                                unsigned doff[NDENSE]) {
    unsigned acc = 0;
    for (int ll = 0; ll < NDENSE; ++ll) {
        unsigned S = (unsigned)resolutions[ll] + 1u;
        doff[ll] = acc;
        acc += S * S * S;
    }
    return acc;
}

// ---- pre-pass: copy hashed coarse tables into dense 3D arrays in ws ----
// dense[doff_l + x + S*(y + S*z)] = emb[off_l + (hash3(x,y,z) mod size)]
__global__ __launch_bounds__(256) void densify_kernel(
    const float* __restrict__ emb,
    const int*   __restrict__ offsets,
    const int*   __restrict__ resolutions,
    float*       __restrict__ ws)
{
    unsigned doff[NDENSE];
    unsigned total = dense_total(resolutions, doff);
    if (total > PREPASS_CAP) total = PREPASS_CAP;  // guard (main kernel falls back too)
    unsigned tid = blockIdx.x * 256u + threadIdx.x;
    if (tid >= total) return;
    int l = 0;
    while (l < NDENSE - 1 && tid >= doff[l + 1]) ++l;
    unsigned idx = tid - doff[l];
    unsigned S = (unsigned)resolutions[l] + 1u;
    unsigned x = idx % S;
    unsigned t = idx / S;
    unsigned y = t % S;
    unsigned z = t / S;
    unsigned off  = (unsigned)offsets[l];
    unsigned size = (unsigned)offsets[l + 1] - off;
    unsigned mask = size - 1u;
    unsigned h = hash3(x, y, z);
    unsigned hm = ((size & mask) == 0u) ? (h & mask) : (h % size);
    const f32x2* src = reinterpret_cast<const f32x2*>(emb) + off + hm;
    f32x2* dst = reinterpret_cast<f32x2*>(ws) + tid;
    *dst = *src;   // gathered read, coalesced write
}

// ---- main: one block = one level x 256 points ----
// g = blockIdx.x & 15 -> level; XCD = g & 7 (round-robin dispatch heuristic):
// fine levels 8..15 on XCD 0..7 (g=0..7), level 7 joins XCD0 (g=8),
// dense levels 0..6 on XCD 1..7 (g=9..15). Each XCD: ~1 fine table + 1 small
// dense table resident in its 4 MiB L2.
__global__ __launch_bounds__(256) void encode_kernel(
    const float* __restrict__ xyz,
    const float* __restrict__ emb,
    const int*   __restrict__ offsets,
    const int*   __restrict__ resolutions,
    const float* __restrict__ min_xyz,
    const float* __restrict__ max_xyz,
    const float* __restrict__ dense,
    float*       __restrict__ out,
    int B, int use_dense)
{
    const int g = blockIdx.x & 15;
    const int chunk = blockIdx.x >> 4;
    const int l = (g < 8) ? (8 + g) : ((g == 8) ? 7 : (g - 9));
    const int p = chunk * 256 + (int)threadIdx.x;
    if (p >= B) return;

    const float res = (float)resolutions[l];
    const unsigned off  = (unsigned)offsets[l];
    const unsigned size = (unsigned)offsets[l + 1] - off;
    const unsigned mask = size - 1u;
    const bool pow2 = (size & mask) == 0u;
    const float mn0 = min_xyz[0], mn1 = min_xyz[1], mn2 = min_xyz[2];
    const float mx0 = max_xyz[0], mx1 = max_xyz[1], mx2 = max_xyz[2];

    const float x = xyz[p * 3 + 0];
    const float y = xyz[p * 3 + 1];
    const float z = xyz[p * 3 + 2];
    // bit-exact fp32 chain (matches reference op order)
    const float ux = (x - mn0) / (mx0 - mn0);
    const float uy = (y - mn1) / (mx1 - mn1);
    const float uz = (z - mn2) / (mx2 - mn2);
    const bool valid = (ux >= 0.0f) & (ux <= 1.0f) &
                       (uy >= 0.0f) & (uy <= 1.0f) &
                       (uz >= 0.0f) & (uz <= 1.0f);

    const float rm1 = res - 1.0f;
    const float px = ux * res, py = uy * res, pz = uz * res;
    const float p0x = fminf(fmaxf(floorf(px), 0.0f), rm1);
    const float p0y = fminf(fmaxf(floorf(py), 0.0f), rm1);
    const float p0z = fminf(fmaxf(floorf(pz), 0.0f), rm1);
    const float fx = px - p0x, fy = py - p0y, fz = pz - p0z;
    const float gx = 1.0f - fx, gy = 1.0f - fy, gz = 1.0f - fz;
    const unsigned cx0 = (unsigned)p0x;
    const unsigned cy0 = (unsigned)p0y;
    const unsigned cz0 = (unsigned)p0z;

    float o0 = 0.0f, o1 = 0.0f;

    bool dense_ok = false;
    unsigned doff[NDENSE];
    if (use_dense && l < NDENSE) {
        unsigned total = dense_total(resolutions, doff);
        dense_ok = (total <= PREPASS_CAP);
    }

    if (dense_ok) {
        // dense 3D layout: x-pairs adjacent -> 4 x 16B loads (values identical
        // to hashed gathers, so result is bit-identical)
        const unsigned S = (unsigned)resolutions[l] + 1u;
        const f32x2* lvl = reinterpret_cast<const f32x2*>(dense) + doff[l];
        const unsigned base = cx0 + S * (cy0 + S * cz0);
        f32x4 e00, e10, e01, e11;
        __builtin_memcpy(&e00, lvl + base,             16);  // (0,0,0),(1,0,0)
        __builtin_memcpy(&e10, lvl + base + S,         16);  // (0,1,0),(1,1,0)
        __builtin_memcpy(&e01, lvl + base + S * S,     16);  // (0,0,1),(1,0,1)
        __builtin_memcpy(&e11, lvl + base + S * S + S, 16);  // (0,1,1),(1,1,1)
        // accumulate in c = bx + 2*by + 4*bz order (same as hashed path)
        o0 += (gx * gy * gz) * e00.x;  o1 += (gx * gy * gz) * e00.y;  // c=0
        o0 += (fx * gy * gz) * e00.z;  o1 += (fx * gy * gz) * e00.w;  // c=1
        o0 += (gx * fy * gz) * e10.x;  o1 += (gx * fy * gz) * e10.y;  // c=2
        o0 += (fx * fy * gz) * e10.z;  o1 += (fx * fy * gz) * e10.w;  // c=3
        o0 += (gx * gy * fz) * e01.x;  o1 += (gx * gy * fz) * e01.y;  // c=4
        o0 += (fx * gy * fz) * e01.z;  o1 += (fx * gy * fz) * e01.w;  // c=5
        o0 += (gx * fy * fz) * e11.x;  o1 += (gx * fy * fz) * e11.y;  // c=6
        o0 += (fx * fy * fz) * e11.z;  o1 += (fx * fy * fz) * e11.w;  // c=7
    } else {
        const f32x2* lvl = reinterpret_cast<const f32x2*>(emb) + off;
#pragma unroll
        for (int c = 0; c < 8; ++c) {
            unsigned bx = (unsigned)(c & 1);
            unsigned by = (unsigned)((c >> 1) & 1);
            unsigned bz = (unsigned)((c >> 2) & 1);
            unsigned h = hash3(cx0 + bx, cy0 + by, cz0 + bz);
            unsigned hm = pow2 ? (h & mask) : (h % size);
            f32x2 e = lvl[hm];
            float w = (bx ? fx : gx) * (by ? fy : gy);
            w = w * (bz ? fz : gz);
            o0 += w * e.x;
            o1 += w * e.y;
        }
    }

    if (!valid) { o0 = 0.0f; o1 = 0.0f; }
    f32x2 r; r.x = o0; r.y = o1;
    f32x2* op = reinterpret_cast<f32x2*>(out + (size_t)p * (NLVL * 2) + l * 2);
    __builtin_nontemporal_store(r, op);
}

extern "C" void kernel_launch(void* const* d_in, const int* in_sizes, int n_in,
                              void* d_out, int out_size, void* d_ws, size_t ws_size,
                              hipStream_t stream) {
    const float* xyz        = (const float*)d_in[0];
    const float* embeddings = (const float*)d_in[1];
    const int*   offsets    = (const int*)d_in[2];
    const int*   resolutions= (const int*)d_in[3];
    const float* min_xyz    = (const float*)d_in[4];
    const float* max_xyz    = (const float*)d_in[5];
    float* out = (float*)d_out;

    int B = in_sizes[0] / 3;
    int use_dense = (ws_size >= (size_t)PREPASS_CAP * 8) ? 1 : 0;

    if (use_dense) {
        int pgrid = (PREPASS_CAP + 255) / 256;
        densify_kernel<<<pgrid, 256, 0, stream>>>(
            embeddings, offsets, resolutions, (float*)d_ws);
    }
    int nchunks = (B + 255) / 256;
    int grid = nchunks * NLVL;
    encode_kernel<<<grid, 256, 0, stream>>>(
        xyz, embeddings, offsets, resolutions, min_xyz, max_xyz,
        (const float*)d_ws, out, B, use_dense);
}

// Round 6
// 709.955 us; speedup vs baseline: 1.0162x; 1.0042x over previous
//
#include <hip/hip_runtime.h>

#define NLVL 16
#define NDENSE 7            // levels 0..6: (res+1)^3 < 2^19 -> densify
#define PREPASS_CAP 600000  // max dense entries the pre-pass covers

typedef float f32x2 __attribute__((ext_vector_type(2)));
typedef float f32x4 __attribute__((ext_vector_type(4)));

__device__ __forceinline__ unsigned hash3(unsigned x, unsigned y, unsigned z) {
    return x ^ (y * 2654435761u) ^ (z * 805459861u);
}

__device__ __forceinline__ unsigned dense_total(const int* __restrict__ resolutions,
                                                unsigned doff[NDENSE]) {
    unsigned acc = 0;
    for (int ll = 0; ll < NDENSE; ++ll) {
        unsigned S = (unsigned)resolutions[ll] + 1u;
        doff[ll] = acc;
        acc += S * S * S;
    }
    return acc;
}

// ---- pre-pass: copy hashed coarse tables into dense 3D arrays in ws ----
__global__ __launch_bounds__(256) void densify_kernel(
    const float* __restrict__ emb,
    const int*   __restrict__ offsets,
    const int*   __restrict__ resolutions,
    float*       __restrict__ ws)
{
    unsigned doff[NDENSE];
    unsigned total = dense_total(resolutions, doff);
    if (total > PREPASS_CAP) total = PREPASS_CAP;
    unsigned tid = blockIdx.x * 256u + threadIdx.x;
    if (tid >= total) return;
    int l = 0;
    while (l < NDENSE - 1 && tid >= doff[l + 1]) ++l;
    unsigned idx = tid - doff[l];
    unsigned S = (unsigned)resolutions[l] + 1u;
    unsigned x = idx % S;
    unsigned t = idx / S;
    unsigned y = t % S;
    unsigned z = t / S;
    unsigned off  = (unsigned)offsets[l];
    unsigned size = (unsigned)offsets[l + 1] - off;
    unsigned mask = size - 1u;
    unsigned h = hash3(x, y, z);
    unsigned hm = ((size & mask) == 0u) ? (h & mask) : (h % size);
    const f32x2* src = reinterpret_cast<const f32x2*>(emb) + off + hm;
    f32x2* dst = reinterpret_cast<f32x2*>(ws) + tid;
    *dst = *src;
}

// ---- main: one block = one level x 256 points ----
// XCD = blockIdx.x % 8 (round-robin dispatch heuristic).
// g = blockIdx.x & 15:
//   g in 0..7  -> PINNED fine level l = 8+g on XCD g (table L2-resident).
//   g in 8..15 -> SPREAD levels 0..7 rotating across XCDs every 64 chunks:
//                 l = ((g-8) + (chunk>>6)) & 7. Level 7 (hashed, L3-hot) and
//                 the dense coarse levels each cost every XCD only 1/8 duty.
__global__ __launch_bounds__(256) void encode_kernel(
    const float* __restrict__ xyz,
    const float* __restrict__ emb,
    const int*   __restrict__ offsets,
    const int*   __restrict__ resolutions,
    const float* __restrict__ min_xyz,
    const float* __restrict__ max_xyz,
    const float* __restrict__ dense,
    float*       __restrict__ out,
    int B, int use_dense)
{
    const int g = blockIdx.x & 15;
    const int chunk = blockIdx.x >> 4;
    const int l = (g < 8) ? (8 + g) : (((g - 8) + (chunk >> 6)) & 7);
    const int p = chunk * 256 + (int)threadIdx.x;
    if (p >= B) return;

    const float res = (float)resolutions[l];
    const unsigned off  = (unsigned)offsets[l];
    const unsigned size = (unsigned)offsets[l + 1] - off;
    const unsigned mask = size - 1u;
    const bool pow2 = (size & mask) == 0u;
    const float mn0 = min_xyz[0], mn1 = min_xyz[1], mn2 = min_xyz[2];
    const float mx0 = max_xyz[0], mx1 = max_xyz[1], mx2 = max_xyz[2];

    const float x = xyz[p * 3 + 0];
    const float y = xyz[p * 3 + 1];
    const float z = xyz[p * 3 + 2];
    // bit-exact fp32 chain (matches reference op order)
    const float ux = (x - mn0) / (mx0 - mn0);
    const float uy = (y - mn1) / (mx1 - mn1);
    const float uz = (z - mn2) / (mx2 - mn2);
    const bool valid = (ux >= 0.0f) & (ux <= 1.0f) &
                       (uy >= 0.0f) & (uy <= 1.0f) &
                       (uz >= 0.0f) & (uz <= 1.0f);

    const float rm1 = res - 1.0f;
    const float px = ux * res, py = uy * res, pz = uz * res;
    const float p0x = fminf(fmaxf(floorf(px), 0.0f), rm1);
    const float p0y = fminf(fmaxf(floorf(py), 0.0f), rm1);
    const float p0z = fminf(fmaxf(floorf(pz), 0.0f), rm1);
    const float fx = px - p0x, fy = py - p0y, fz = pz - p0z;
    const float gx = 1.0f - fx, gy = 1.0f - fy, gz = 1.0f - fz;
    const unsigned cx0 = (unsigned)p0x;
    const unsigned cy0 = (unsigned)p0y;
    const unsigned cz0 = (unsigned)p0z;

    float o0 = 0.0f, o1 = 0.0f;

    bool dense_ok = false;
    unsigned doff[NDENSE];
    if (use_dense && l < NDENSE) {
        unsigned total = dense_total(resolutions, doff);
        dense_ok = (total <= PREPASS_CAP);
    }

    if (dense_ok) {
        const unsigned S = (unsigned)resolutions[l] + 1u;
        const f32x2* lvl = reinterpret_cast<const f32x2*>(dense) + doff[l];
        const unsigned base = cx0 + S * (cy0 + S * cz0);
        f32x4 e00, e10, e01, e11;
        __builtin_memcpy(&e00, lvl + base,             16);
        __builtin_memcpy(&e10, lvl + base + S,         16);
        __builtin_memcpy(&e01, lvl + base + S * S,     16);
        __builtin_memcpy(&e11, lvl + base + S * S + S, 16);
        o0 += (gx * gy * gz) * e00.x;  o1 += (gx * gy * gz) * e00.y;  // c=0
        o0 += (fx * gy * gz) * e00.z;  o1 += (fx * gy * gz) * e00.w;  // c=1
        o0 += (gx * fy * gz) * e10.x;  o1 += (gx * fy * gz) * e10.y;  // c=2
        o0 += (fx * fy * gz) * e10.z;  o1 += (fx * fy * gz) * e10.w;  // c=3
        o0 += (gx * gy * fz) * e01.x;  o1 += (gx * gy * fz) * e01.y;  // c=4
        o0 += (fx * gy * fz) * e01.z;  o1 += (fx * gy * fz) * e01.w;  // c=5
        o0 += (gx * fy * fz) * e11.x;  o1 += (gx * fy * fz) * e11.y;  // c=6
        o0 += (fx * fy * fz) * e11.z;  o1 += (fx * fy * fz) * e11.w;  // c=7
    } else {
        const f32x2* lvl = reinterpret_cast<const f32x2*>(emb) + off;
#pragma unroll
        for (int c = 0; c < 8; ++c) {
            unsigned bx = (unsigned)(c & 1);
            unsigned by = (unsigned)((c >> 1) & 1);
            unsigned bz = (unsigned)((c >> 2) & 1);
            unsigned h = hash3(cx0 + bx, cy0 + by, cz0 + bz);
            unsigned hm = pow2 ? (h & mask) : (h % size);
            f32x2 e = lvl[hm];
            float w = (bx ? fx : gx) * (by ? fy : gy);
            w = w * (bz ? fz : gz);
            o0 += w * e.x;
            o1 += w * e.y;
        }
    }

    if (!valid) { o0 = 0.0f; o1 = 0.0f; }
    f32x2 r; r.x = o0; r.y = o1;
    f32x2* op = reinterpret_cast<f32x2*>(out + (size_t)p * (NLVL * 2) + l * 2);
    __builtin_nontemporal_store(r, op);
}

extern "C" void kernel_launch(void* const* d_in, const int* in_sizes, int n_in,
                              void* d_out, int out_size, void* d_ws, size_t ws_size,
                              hipStream_t stream) {
    const float* xyz        = (const float*)d_in[0];
    const float* embeddings = (const float*)d_in[1];
    const int*   offsets    = (const int*)d_in[2];
    const int*   resolutions= (const int*)d_in[3];
    const float* min_xyz    = (const float*)d_in[4];
    const float* max_xyz    = (const float*)d_in[5];
    float* out = (float*)d_out;

    int B = in_sizes[0] / 3;
    int use_dense = (ws_size >= (size_t)PREPASS_CAP * 8) ? 1 : 0;

    if (use_dense) {
        int pgrid = (PREPASS_CAP + 255) / 256;
        densify_kernel<<<pgrid, 256, 0, stream>>>(
            embeddings, offsets, resolutions, (float*)d_ws);
    }
    int nchunks = (B + 255) / 256;
    int grid = nchunks * NLVL;
    encode_kernel<<<grid, 256, 0, stream>>>(
        xyz, embeddings, offsets, resolutions, min_xyz, max_xyz,
        (const float*)d_ws, out, B, use_dense);
}